// Round 5
// baseline (361.093 us; speedup 1.0000x reference)
//
#include <hip/hip_runtime.h>

#define LDIM 8192
#define HDIM 16
#define DDIM 64
#define NHEADPAIR 64          // N*H
#define ROWSTRIDE 1024        // H*D floats between consecutive l for fixed h
#define KVSZ 4160             // 64*64 KV + 64 ksum
#define EPSF 1e-6f

__device__ __forceinline__ float featmap(float x) {
    // elu(x)+1 : x>0 -> x+1 ; x<=0 -> exp(x)
    return x > 0.0f ? x + 1.0f : __expf(x);
}

// ---------------- Phase 1: partial KV[d][m] and Ksum[d] per (n,h,chunk) -------------
// grid = (nh=64, chunkgroup=16): consecutive blocks = all 16 heads of one n over the
// SAME l-range -> their interleaved 256B segments merge into dense HBM streams.
// Waves interleave rows (s*4+w) so the block walks l contiguously.
// Thread tile 4d x 16m: featmap dup x4 (was x8).
__global__ __launch_bounds__(256) void kv_partial_kernel(
    const float* __restrict__ Kp, const float* __restrict__ Vp,
    float* __restrict__ part, int chunks, int rowsPerChunk)
{
    const int nh   = blockIdx.x;            // 0..63
    const int n    = nh >> 4;
    const int h    = nh & 15;
    const int wave = threadIdx.x >> 6;      // 0..3
    const int lane = threadIdx.x & 63;
    const int chunk = blockIdx.y * 4 + wave;
    const int d0 = (lane & 15) * 4;         // 16 d-groups
    const int m0 = (lane >> 4) * 16;        // 4 m-groups

    const size_t base = (((size_t)n * LDIM) * HDIM + h) * DDIM
                      + ((size_t)blockIdx.y * 4 * rowsPerChunk + wave) * ROWSTRIDE;
    const float* Kb = Kp + base;
    const float* Vb = Vp + base;

    float acc[4][16];
    float ksum[4];
#pragma unroll
    for (int i = 0; i < 4; ++i) {
        ksum[i] = 0.0f;
#pragma unroll
        for (int j = 0; j < 16; ++j) acc[i][j] = 0.0f;
    }

    // 1-deep software pipeline
    float4 k0  = *(const float4*)(Kb + d0);
    float4 v0a = *(const float4*)(Vb + m0);
    float4 v0b = *(const float4*)(Vb + m0 + 4);
    float4 v0c = *(const float4*)(Vb + m0 + 8);
    float4 v0d = *(const float4*)(Vb + m0 + 12);

    for (int s = 0; s < rowsPerChunk; ++s) {
        const int sn = (s + 1 < rowsPerChunk) ? s + 1 : s;
        const float* kr = Kb + (size_t)sn * 4 * ROWSTRIDE;
        const float* vr = Vb + (size_t)sn * 4 * ROWSTRIDE;
        float4 k1  = *(const float4*)(kr + d0);
        float4 v1a = *(const float4*)(vr + m0);
        float4 v1b = *(const float4*)(vr + m0 + 4);
        float4 v1c = *(const float4*)(vr + m0 + 8);
        float4 v1d = *(const float4*)(vr + m0 + 12);

        float kf[4] = { featmap(k0.x), featmap(k0.y), featmap(k0.z), featmap(k0.w) };
        float vv[16] = { v0a.x, v0a.y, v0a.z, v0a.w,  v0b.x, v0b.y, v0b.z, v0b.w,
                         v0c.x, v0c.y, v0c.z, v0c.w,  v0d.x, v0d.y, v0d.z, v0d.w };
#pragma unroll
        for (int i = 0; i < 4; ++i) {
            ksum[i] += kf[i];
#pragma unroll
            for (int j = 0; j < 16; ++j) acc[i][j] += kf[i] * vv[j];
        }
        k0 = k1; v0a = v1a; v0b = v1b; v0c = v1c; v0d = v1d;
    }

    float* p = part + (size_t)(nh * chunks + chunk) * KVSZ;
#pragma unroll
    for (int i = 0; i < 4; ++i) {
#pragma unroll
        for (int jj = 0; jj < 4; ++jj) {
            *(float4*)(p + (d0 + i) * 64 + m0 + jj * 4) =
                make_float4(acc[i][jj * 4 + 0], acc[i][jj * 4 + 1],
                            acc[i][jj * 4 + 2], acc[i][jj * 4 + 3]);
        }
    }
    if (m0 == 0) {
#pragma unroll
        for (int i = 0; i < 4; ++i) p[4096 + d0 + i] = ksum[i];
    }
}

// ---------------- Phase 1b: deterministic parallel reduce of partials ---------------
__global__ __launch_bounds__(256) void kv_reduce_kernel(
    const float* __restrict__ part, float* __restrict__ kvf, int chunks)
{
    const int nh = blockIdx.x;
    const int e  = blockIdx.y * 256 + threadIdx.x;
    if (e >= KVSZ) return;
    float s = 0.0f;
    for (int c = 0; c < chunks; ++c)
        s += part[(size_t)(nh * chunks + c) * KVSZ + e];
    kvf[(size_t)nh * KVSZ + e] = s;
}

// ---------------- Phase 2: out[l][m] = Z * sum_d fm(Q[l,d]) * KV[m][d] ---------------
// Thread tile 8 rows x 8 m: LDS 0.5 B/FMA. grid = (nh, lblock) for head-dense HBM.
__global__ __launch_bounds__(256) void attn_out_kernel(
    const float* __restrict__ Qp, const float* __restrict__ kvf,
    float* __restrict__ out)
{
    __shared__ float Bt[64][68];   // Bt[d][m] = KV[m][d]; pad 68 keeps 16B align, spreads banks
    __shared__ float ks[64];

    const int nh = blockIdx.x;
    const int n  = nh >> 4;
    const int h  = nh & 15;
    const float* kv = kvf + (size_t)nh * KVSZ;

    for (int e = threadIdx.x; e < 4096; e += 256) {
        int m = e >> 6, d = e & 63;
        Bt[d][m] = kv[e];
    }
    if (threadIdx.x < 64) ks[threadIdx.x] = kv[4096 + threadIdx.x];
    __syncthreads();

    const int wave = threadIdx.x >> 6;
    const int lane = threadIdx.x & 63;
    const int mg = lane & 7;
    const int lg = lane >> 3;
    const int m0 = mg * 8;
    const int l0 = blockIdx.y * 256 + wave * 64 + lg * 8;

    const float* Qb = Qp + (((size_t)n * LDIM) * HDIM + h) * DDIM;

    float acc[8][8];
    float zacc[8];
#pragma unroll
    for (int i = 0; i < 8; ++i) {
        zacc[i] = 0.0f;
#pragma unroll
        for (int j = 0; j < 8; ++j) acc[i][j] = 0.0f;
    }

#pragma unroll
    for (int c8 = 0; c8 < 8; ++c8) {
        const int dd = c8 * 8;
        float qf[8][8];
#pragma unroll
        for (int i = 0; i < 8; ++i) {
            const float* qr = Qb + (size_t)(l0 + i) * ROWSTRIDE + dd;
            float4 a = *(const float4*)(qr);
            float4 b = *(const float4*)(qr + 4);
            qf[i][0] = featmap(a.x); qf[i][1] = featmap(a.y);
            qf[i][2] = featmap(a.z); qf[i][3] = featmap(a.w);
            qf[i][4] = featmap(b.x); qf[i][5] = featmap(b.y);
            qf[i][6] = featmap(b.z); qf[i][7] = featmap(b.w);
        }
#pragma unroll
        for (int j = 0; j < 8; ++j) {
            const float ksj = ks[dd + j];
            float4 b0 = *(const float4*)(&Bt[dd + j][m0]);
            float4 b1 = *(const float4*)(&Bt[dd + j][m0 + 4]);
#pragma unroll
            for (int i = 0; i < 8; ++i) {
                const float q = qf[i][j];
                zacc[i]   += q * ksj;
                acc[i][0] += q * b0.x; acc[i][1] += q * b0.y;
                acc[i][2] += q * b0.z; acc[i][3] += q * b0.w;
                acc[i][4] += q * b1.x; acc[i][5] += q * b1.y;
                acc[i][6] += q * b1.z; acc[i][7] += q * b1.w;
            }
        }
    }

#pragma unroll
    for (int i = 0; i < 8; ++i) {
        const float z = 1.0f / (zacc[i] + EPSF);
        float* orow = out + (((size_t)n * LDIM + (l0 + i)) * HDIM + h) * DDIM + m0;
        *(float4*)(orow)     = make_float4(acc[i][0] * z, acc[i][1] * z,
                                           acc[i][2] * z, acc[i][3] * z);
        *(float4*)(orow + 4) = make_float4(acc[i][4] * z, acc[i][5] * z,
                                           acc[i][6] * z, acc[i][7] * z);
    }
}

extern "C" void kernel_launch(void* const* d_in, const int* in_sizes, int n_in,
                              void* d_out, int out_size, void* d_ws, size_t ws_size,
                              hipStream_t stream) {
    const float* Q = (const float*)d_in[0];
    const float* K = (const float*)d_in[1];
    const float* V = (const float*)d_in[2];
    float* out = (float*)d_out;
    float* ws  = (float*)d_ws;

    // pick chunk count (per head-pair) that fits the workspace
    int chunks = 64;
    while (chunks > 4 &&
           ((size_t)NHEADPAIR * chunks + NHEADPAIR) * KVSZ * sizeof(float) > ws_size)
        chunks >>= 1;
    const int rowsPerChunk = LDIM / chunks;

    float* part = ws;
    float* kvf  = ws + (size_t)NHEADPAIR * chunks * KVSZ;

    dim3 g1(NHEADPAIR, chunks / 4);
    kv_partial_kernel<<<g1, 256, 0, stream>>>(K, V, part, chunks, rowsPerChunk);
    dim3 gr(NHEADPAIR, (KVSZ + 255) / 256);
    kv_reduce_kernel<<<gr, 256, 0, stream>>>(part, kvf, chunks);
    dim3 g2(NHEADPAIR, LDIM / 256);
    attn_out_kernel<<<g2, 256, 0, stream>>>(Q, kvf, out);
}